// Round 1
// baseline (231.141 us; speedup 1.0000x reference)
//
#include <hip/hip_runtime.h>
#include <cmath>

#define THREADS 256
#define NCELL 10
#define DDIM 9

struct Basis { float Bt[DDIM][2 * NCELL]; }; // Bt[t][l] = B[l][t]

// Reproduce numpy.linalg.svd(L) Vt[11:] rows: LAPACK dgesdd Path 4t leaves
// rows m..n-1 of VT equal to the LQ-factorization orthogonal complement
// (dgelqf + dorglq). Replicate dlarfg/dgelq2/dorgl2 in double precision.
static void compute_basis_host(Basis* bs) {
  double L[11][20];
  for (int r = 0; r < 11; ++r)
    for (int c = 0; c < 20; ++c) L[r][c] = 0.0;
  for (int k = 1; k < NCELL; ++k) {
    double xk = (double)k / (double)NCELL;
    L[k - 1][2 * (k - 1)] = xk;
    L[k - 1][2 * (k - 1) + 1] = 1.0;
    L[k - 1][2 * k] = -xk;
    L[k - 1][2 * k + 1] = -1.0;
  }
  L[NCELL - 1][1] = 1.0;
  L[NCELL][2 * (NCELL - 1)] = 1.0;
  L[NCELL][2 * (NCELL - 1) + 1] = 1.0;

  double v[11][20];
  double tau[11];
  for (int i = 0; i < 11; ++i) {
    double alpha = L[i][i];
    double xn2 = 0.0;
    for (int l = i + 1; l < 20; ++l) xn2 += L[i][l] * L[i][l];
    double xnorm = sqrt(xn2);
    for (int l = 0; l < 20; ++l) v[i][l] = 0.0;
    v[i][i] = 1.0;
    if (xnorm == 0.0) {
      tau[i] = 0.0;
    } else {
      double beta = sqrt(alpha * alpha + xn2);
      if (alpha >= 0.0) beta = -beta;        // dlarfg: beta = -sign(alpha)*norm
      tau[i] = (beta - alpha) / beta;
      double sc = 1.0 / (alpha - beta);
      for (int l = i + 1; l < 20; ++l) v[i][l] = L[i][l] * sc;
      L[i][i] = beta;
      // apply H(i) from the right to remaining rows (dlarf 'Right')
      for (int j = i + 1; j < 11; ++j) {
        double w = 0.0;
        for (int l = i; l < 20; ++l) w += L[j][l] * v[i][l];
        w *= tau[i];
        for (int l = i; l < 20; ++l) L[j][l] -= w * v[i][l];
      }
    }
  }
  // Rows 11..19 of Q = H(11)...H(1):  q_row_j^T = H(1)...H(11) e_j
  for (int j = 11; j < 20; ++j) {
    double q[20];
    for (int l = 0; l < 20; ++l) q[l] = 0.0;
    q[j] = 1.0;
    for (int i = 10; i >= 0; --i) {
      double w = 0.0;
      for (int l = i; l < 20; ++l) w += v[i][l] * q[l];
      w *= tau[i];
      for (int l = i; l < 20; ++l) q[l] -= w * v[i][l];
    }
    for (int l = 0; l < 20; ++l) bs->Bt[j - 11][l] = (float)q[l];
  }
}

__device__ __forceinline__ void mlp_eval(float xin,
    const float* __restrict__ w0, const float* __restrict__ b0,
    const float* __restrict__ w1, const float* __restrict__ b1,
    const float* __restrict__ w2, const float* __restrict__ b2,
    const float* __restrict__ w3, const float* __restrict__ b3,
    float th[DDIM]) {
  float h0[10], h1[10], h2[10];
#pragma unroll
  for (int j = 0; j < 10; ++j) h0[j] = xin * w0[j] + b0[j];
#pragma unroll
  for (int j = 0; j < 10; ++j) {
    float s = b1[j];
#pragma unroll
    for (int r = 0; r < 10; ++r) s += h0[r] * w1[r * 10 + j];
    h1[j] = fmaxf(s, 0.0f);
  }
#pragma unroll
  for (int j = 0; j < 10; ++j) {
    float s = b2[j];
#pragma unroll
    for (int r = 0; r < 10; ++r) s += h1[r] * w2[r * 10 + j];
    h2[j] = fmaxf(s, 0.0f);
  }
#pragma unroll
  for (int j = 0; j < DDIM; ++j) {
    float s = b3[j];
#pragma unroll
    for (int r = 0; r < 10; ++r) s += h2[r] * w3[r * DDIM + j];
    th[j] = s;
  }
}

__device__ __forceinline__ void write_A(const float th[DDIM], const Basis& bb,
                                        float2* abcol) {
#pragma unroll
  for (int l = 0; l < NCELL; ++l) {
    float a = 0.0f, b = 0.0f;
#pragma unroll
    for (int t = 0; t < DDIM; ++t) {
      a += th[t] * bb.Bt[t][2 * l];
      b += th[t] * bb.Bt[t][2 * l + 1];
    }
    abcol[l * THREADS] = make_float2(a, b);
  }
}

__device__ __forceinline__ void flow_dev(float x0, const float2* abcol,
                                         float& zo, float& ldo) {
  float phi = x0;
  float t = 1.0f;
  float ld = 0.0f;
  int c = (int)(x0 * 10.0f);
  c = c < 0 ? 0 : (c > 9 ? 9 : c);
#pragma unroll
  for (int it = 0; it < NCELL; ++it) {
    float2 ab = abcol[c * THREADS];
    float a = ab.x, b = ab.y;
    float v = __fmul_rn(a, phi) + b;             // no fp-contract: match mul+add
    bool lin = fabsf(a) < 1e-10f;
    float sa = lin ? 1.0f : a;
    float xc = ((v >= 0.0f) ? (float)(c + 1) : (float)c) / 10.0f;
    float bsa = b / sa;                          // IEEE div, reused like reference
    float den = phi + bsa;
    den = (fabsf(den) < 1e-30f) ? 1e-30f : den;
    float t_exp = logf(fmaxf((xc + bsa) / den, 1e-30f)) / sa;
    float sb = (fabsf(b) < 1e-30f) ? 1.0f : b;
    float thit = lin ? ((xc - phi) / sb) : t_exp;
    thit = (fabsf(v) < 1e-14f) ? __builtin_inff() : thit;
    bool cross = thit < t;
    float dt = cross ? thit : t;
    float E = expf(__fmul_rn(a, dt));
    float phi_lin = phi + __fmul_rn(b, dt);
    float phi_exp = __fmul_rn(phi + bsa, E) - bsa; // no fma: match mul then sub
    float phi_new = lin ? phi_lin : phi_exp;
    phi_new = cross ? xc : phi_new;
    bool active = t > 0.0f;
    phi = active ? phi_new : phi;
    ld += active ? __fmul_rn(a, dt) : 0.0f;
    t = active ? (t - dt) : t;
    int cstep = (v >= 0.0f) ? 1 : -1;
    int cn = c + cstep;
    cn = cn < 0 ? 0 : (cn > 9 ? 9 : cn);
    c = (active && cross) ? cn : c;
  }
  zo = phi;
  ldo = ld;
}

__global__ __launch_bounds__(THREADS) void cpab2d_kernel(
    const float* __restrict__ x,
    const float* __restrict__ m1w0, const float* __restrict__ m1b0,
    const float* __restrict__ m1w1, const float* __restrict__ m1b1,
    const float* __restrict__ m1w2, const float* __restrict__ m1b2,
    const float* __restrict__ m1w3, const float* __restrict__ m1b3,
    const float* __restrict__ m2w0, const float* __restrict__ m2b0,
    const float* __restrict__ m2w1, const float* __restrict__ m2b1,
    const float* __restrict__ m2w2, const float* __restrict__ m2b2,
    const float* __restrict__ m2w3, const float* __restrict__ m2b3,
    float* __restrict__ out, int n, Basis bb) {
  __shared__ float2 AB[NCELL][THREADS];   // [cell][tid] -> conflict-free dyn read
  int i = blockIdx.x * THREADS + threadIdx.x;
  if (i >= n) return;

  float2 xi = reinterpret_cast<const float2*>(x)[i];
  // xs = x[:, [1,0]]: x1 = x[:,1], x2 = x[:,0]; both clipped first
  float x2v = fminf(fmaxf(xi.x, 1e-7f), 1.0f - 1e-7f);
  float x1v = fminf(fmaxf(xi.y, 1e-7f), 1.0f - 1e-7f);

  float2* abcol = &AB[0][threadIdx.x];
  float th[DDIM];

  // theta2 = mlp(x1, m2); z2,g2 = flow(x2, theta2)
  mlp_eval(x1v, m2w0, m2b0, m2w1, m2b1, m2w2, m2b2, m2w3, m2b3, th);
  write_A(th, bb, abcol);
  float z2, ld2;
  flow_dev(x2v, abcol, z2, ld2);

  // theta1 = mlp(z2, m1); z1,g1 = flow(x1, theta1)
  mlp_eval(z2, m1w0, m1b0, m1w1, m1b1, m1w2, m1b2, m1w3, m1b3, th);
  write_A(th, bb, abcol);
  float z1, ld1;
  flow_dev(x1v, abcol, z1, ld1);

  // z = [z2, z1]; log_dz_dx = [ld2, ld1]
  reinterpret_cast<float2*>(out)[i] = make_float2(z2, z1);
  reinterpret_cast<float2*>(out + 2 * (size_t)n)[i] = make_float2(ld2, ld1);
}

extern "C" void kernel_launch(void* const* d_in, const int* in_sizes, int n_in,
                              void* d_out, int out_size, void* d_ws, size_t ws_size,
                              hipStream_t stream) {
  const float* x    = (const float*)d_in[0];
  const float* m1w0 = (const float*)d_in[1];
  const float* m1b0 = (const float*)d_in[2];
  const float* m1w1 = (const float*)d_in[3];
  const float* m1b1 = (const float*)d_in[4];
  const float* m1w2 = (const float*)d_in[5];
  const float* m1b2 = (const float*)d_in[6];
  const float* m1w3 = (const float*)d_in[7];
  const float* m1b3 = (const float*)d_in[8];
  const float* m2w0 = (const float*)d_in[9];
  const float* m2b0 = (const float*)d_in[10];
  const float* m2w1 = (const float*)d_in[11];
  const float* m2b1 = (const float*)d_in[12];
  const float* m2w2 = (const float*)d_in[13];
  const float* m2b2 = (const float*)d_in[14];
  const float* m2w3 = (const float*)d_in[15];
  const float* m2b3 = (const float*)d_in[16];
  float* out = (float*)d_out;
  int n = in_sizes[0] / 2;

  Basis bs;
  compute_basis_host(&bs);

  dim3 grid((n + THREADS - 1) / THREADS), block(THREADS);
  cpab2d_kernel<<<grid, block, 0, stream>>>(
      x, m1w0, m1b0, m1w1, m1b1, m1w2, m1b2, m1w3, m1b3,
      m2w0, m2b0, m2w1, m2b1, m2w2, m2b2, m2w3, m2b3,
      out, n, bs);
}

// Round 2
// 117.150 us; speedup vs baseline: 1.9730x; 1.9730x over previous
//
#include <hip/hip_runtime.h>
#include <cmath>

#define THREADS 256
#define NCELL 10
#define DDIM 9

struct Basis { float Bt[DDIM][2 * NCELL]; }; // Bt[t][l] = B[l][t]

// Reproduce numpy.linalg.svd(L) Vt[11:] rows: LAPACK dgesdd Path 4t leaves
// rows m..n-1 of VT equal to the LQ-factorization orthogonal complement
// (dgelqf + dorglq). Replicate dlarfg/dgelq2/dorgl2 in double precision.
static void compute_basis_host(Basis* bs) {
  double L[11][20];
  for (int r = 0; r < 11; ++r)
    for (int c = 0; c < 20; ++c) L[r][c] = 0.0;
  for (int k = 1; k < NCELL; ++k) {
    double xk = (double)k / (double)NCELL;
    L[k - 1][2 * (k - 1)] = xk;
    L[k - 1][2 * (k - 1) + 1] = 1.0;
    L[k - 1][2 * k] = -xk;
    L[k - 1][2 * k + 1] = -1.0;
  }
  L[NCELL - 1][1] = 1.0;
  L[NCELL][2 * (NCELL - 1)] = 1.0;
  L[NCELL][2 * (NCELL - 1) + 1] = 1.0;

  double v[11][20];
  double tau[11];
  for (int i = 0; i < 11; ++i) {
    double alpha = L[i][i];
    double xn2 = 0.0;
    for (int l = i + 1; l < 20; ++l) xn2 += L[i][l] * L[i][l];
    double xnorm = sqrt(xn2);
    for (int l = 0; l < 20; ++l) v[i][l] = 0.0;
    v[i][i] = 1.0;
    if (xnorm == 0.0) {
      tau[i] = 0.0;
    } else {
      double beta = sqrt(alpha * alpha + xn2);
      if (alpha >= 0.0) beta = -beta;        // dlarfg: beta = -sign(alpha)*norm
      tau[i] = (beta - alpha) / beta;
      double sc = 1.0 / (alpha - beta);
      for (int l = i + 1; l < 20; ++l) v[i][l] = L[i][l] * sc;
      L[i][i] = beta;
      // apply H(i) from the right to remaining rows (dlarf 'Right')
      for (int j = i + 1; j < 11; ++j) {
        double w = 0.0;
        for (int l = i; l < 20; ++l) w += L[j][l] * v[i][l];
        w *= tau[i];
        for (int l = i; l < 20; ++l) L[j][l] -= w * v[i][l];
      }
    }
  }
  // Rows 11..19 of Q = H(11)...H(1):  q_row_j^T = H(1)...H(11) e_j
  for (int j = 11; j < 20; ++j) {
    double q[20];
    for (int l = 0; l < 20; ++l) q[l] = 0.0;
    q[j] = 1.0;
    for (int i = 10; i >= 0; --i) {
      double w = 0.0;
      for (int l = i; l < 20; ++l) w += v[i][l] * q[l];
      w *= tau[i];
      for (int l = i; l < 20; ++l) q[l] -= w * v[i][l];
    }
    for (int l = 0; l < 20; ++l) bs->Bt[j - 11][l] = (float)q[l];
  }
}

__device__ __forceinline__ void mlp_eval(float xin,
    const float* __restrict__ w0, const float* __restrict__ b0,
    const float* __restrict__ w1, const float* __restrict__ b1,
    const float* __restrict__ w2, const float* __restrict__ b2,
    const float* __restrict__ w3, const float* __restrict__ b3,
    float th[DDIM]) {
  float h0[10], h1[10], h2[10];
#pragma unroll
  for (int j = 0; j < 10; ++j) h0[j] = xin * w0[j] + b0[j];
#pragma unroll
  for (int j = 0; j < 10; ++j) {
    float s = b1[j];
#pragma unroll
    for (int r = 0; r < 10; ++r) s += h0[r] * w1[r * 10 + j];
    h1[j] = fmaxf(s, 0.0f);
  }
#pragma unroll
  for (int j = 0; j < 10; ++j) {
    float s = b2[j];
#pragma unroll
    for (int r = 0; r < 10; ++r) s += h1[r] * w2[r * 10 + j];
    h2[j] = fmaxf(s, 0.0f);
  }
#pragma unroll
  for (int j = 0; j < DDIM; ++j) {
    float s = b3[j];
#pragma unroll
    for (int r = 0; r < 10; ++r) s += h2[r] * w3[r * DDIM + j];
    th[j] = s;
  }
}

__device__ __forceinline__ void write_A(const float th[DDIM], const Basis& bb,
                                        float2* abcol) {
#pragma unroll
  for (int l = 0; l < NCELL; ++l) {
    float a = 0.0f, b = 0.0f;
#pragma unroll
    for (int t = 0; t < DDIM; ++t) {
      a += th[t] * bb.Bt[t][2 * l];
      b += th[t] * bb.Bt[t][2 * l + 1];
    }
    abcol[l * THREADS] = make_float2(a, b);
  }
}

__device__ __forceinline__ void flow_dev(float x0, const float2* abcol,
                                         float& zo, float& ldo) {
  float phi = x0;
  float t = 1.0f;
  float ld = 0.0f;
  int c = (int)(x0 * 10.0f);
  c = c < 0 ? 0 : (c > 9 ? 9 : c);
  for (int it = 0; it < NCELL; ++it) {
    float2 ab = abcol[c * THREADS];
    float a = ab.x, b = ab.y;
    float v = __fmul_rn(a, phi) + b;             // no fp-contract: match mul+add
    bool lin = fabsf(a) < 1e-10f;
    float sa = lin ? 1.0f : a;
    float rsa = __builtin_amdgcn_rcpf(sa);       // v_rcp_f32, ~1 ulp
    float xc = ((v >= 0.0f) ? (float)(c + 1) : (float)c) * 0.1f;
    float bsa = b * rsa;
    float den = phi + bsa;
    den = (fabsf(den) < 1e-30f) ? 1e-30f : den;
    float ratio = (xc + bsa) * __builtin_amdgcn_rcpf(den);
    float t_exp = __logf(fmaxf(ratio, 1e-30f)) * rsa;   // v_log_f32
    float sb = (fabsf(b) < 1e-30f) ? 1.0f : b;
    float thit = lin ? ((xc - phi) * __builtin_amdgcn_rcpf(sb)) : t_exp;
    thit = (fabsf(v) < 1e-14f) ? __builtin_inff() : thit;
    bool cross = thit < t;
    float dt = cross ? thit : t;
    float E = __expf(__fmul_rn(a, dt));          // v_exp_f32
    float phi_lin = phi + __fmul_rn(b, dt);
    float phi_exp = __fmul_rn(phi + bsa, E) - bsa; // no fma: match mul then sub
    float phi_new = lin ? phi_lin : phi_exp;
    phi_new = cross ? xc : phi_new;
    bool active = t > 0.0f;
    phi = active ? phi_new : phi;
    ld += active ? __fmul_rn(a, dt) : 0.0f;
    t = active ? (t - dt) : t;
    int cstep = (v >= 0.0f) ? 1 : -1;
    int cn = c + cstep;
    cn = cn < 0 ? 0 : (cn > 9 ? 9 : cn);
    c = (active && cross) ? cn : c;
    // wave-uniform early exit: inactive lanes never change state, so
    // skipping remaining iterations is exactly the reference semantics.
    if (__all(t <= 0.0f)) break;
  }
  zo = phi;
  ldo = ld;
}

__global__ __launch_bounds__(THREADS) void cpab2d_kernel(
    const float* __restrict__ x,
    const float* __restrict__ m1w0, const float* __restrict__ m1b0,
    const float* __restrict__ m1w1, const float* __restrict__ m1b1,
    const float* __restrict__ m1w2, const float* __restrict__ m1b2,
    const float* __restrict__ m1w3, const float* __restrict__ m1b3,
    const float* __restrict__ m2w0, const float* __restrict__ m2b0,
    const float* __restrict__ m2w1, const float* __restrict__ m2b1,
    const float* __restrict__ m2w2, const float* __restrict__ m2b2,
    const float* __restrict__ m2w3, const float* __restrict__ m2b3,
    float* __restrict__ out, int n, Basis bb) {
  __shared__ float2 AB[NCELL][THREADS];   // [cell][tid] -> conflict-free dyn read
  int i = blockIdx.x * THREADS + threadIdx.x;
  if (i >= n) return;

  float2 xi = reinterpret_cast<const float2*>(x)[i];
  // xs = x[:, [1,0]]: x1 = x[:,1], x2 = x[:,0]; both clipped first
  float x2v = fminf(fmaxf(xi.x, 1e-7f), 1.0f - 1e-7f);
  float x1v = fminf(fmaxf(xi.y, 1e-7f), 1.0f - 1e-7f);

  float2* abcol = &AB[0][threadIdx.x];
  float th[DDIM];

  // theta2 = mlp(x1, m2); z2,g2 = flow(x2, theta2)
  mlp_eval(x1v, m2w0, m2b0, m2w1, m2b1, m2w2, m2b2, m2w3, m2b3, th);
  write_A(th, bb, abcol);
  float z2, ld2;
  flow_dev(x2v, abcol, z2, ld2);

  // theta1 = mlp(z2, m1); z1,g1 = flow(x1, theta1)
  mlp_eval(z2, m1w0, m1b0, m1w1, m1b1, m1w2, m1b2, m1w3, m1b3, th);
  write_A(th, bb, abcol);
  float z1, ld1;
  flow_dev(x1v, abcol, z1, ld1);

  // z = [z2, z1]; log_dz_dx = [ld2, ld1]
  reinterpret_cast<float2*>(out)[i] = make_float2(z2, z1);
  reinterpret_cast<float2*>(out + 2 * (size_t)n)[i] = make_float2(ld2, ld1);
}

extern "C" void kernel_launch(void* const* d_in, const int* in_sizes, int n_in,
                              void* d_out, int out_size, void* d_ws, size_t ws_size,
                              hipStream_t stream) {
  const float* x    = (const float*)d_in[0];
  const float* m1w0 = (const float*)d_in[1];
  const float* m1b0 = (const float*)d_in[2];
  const float* m1w1 = (const float*)d_in[3];
  const float* m1b1 = (const float*)d_in[4];
  const float* m1w2 = (const float*)d_in[5];
  const float* m1b2 = (const float*)d_in[6];
  const float* m1w3 = (const float*)d_in[7];
  const float* m1b3 = (const float*)d_in[8];
  const float* m2w0 = (const float*)d_in[9];
  const float* m2b0 = (const float*)d_in[10];
  const float* m2w1 = (const float*)d_in[11];
  const float* m2b1 = (const float*)d_in[12];
  const float* m2w2 = (const float*)d_in[13];
  const float* m2b2 = (const float*)d_in[14];
  const float* m2w3 = (const float*)d_in[15];
  const float* m2b3 = (const float*)d_in[16];
  float* out = (float*)d_out;
  int n = in_sizes[0] / 2;

  Basis bs;
  compute_basis_host(&bs);

  dim3 grid((n + THREADS - 1) / THREADS), block(THREADS);
  cpab2d_kernel<<<grid, block, 0, stream>>>(
      x, m1w0, m1b0, m1w1, m1b1, m1w2, m1b2, m1w3, m1b3,
      m2w0, m2b0, m2w1, m2b1, m2w2, m2b2, m2w3, m2b3,
      out, n, bs);
}

// Round 3
// 56.169 us; speedup vs baseline: 4.1151x; 2.0857x over previous
//
#include <hip/hip_runtime.h>
#include <cmath>

#define THREADS 256
#define NCELL 10
#define DDIM 9

typedef float f32x2 __attribute__((ext_vector_type(2)));

__device__ __forceinline__ f32x2 fma2(f32x2 a, f32x2 b, f32x2 c) {
  return __builtin_elementwise_fma(a, b, c);   // v_pk_fma_f32 on gfx950
}
__device__ __forceinline__ f32x2 max2(f32x2 a, f32x2 b) {
  return __builtin_elementwise_max(a, b);      // v_pk_max_f32
}

struct Basis { float Bt[DDIM][2 * NCELL]; }; // Bt[t][l] = B[l][t]

// Reproduce numpy.linalg.svd(L) Vt[11:] rows: LAPACK dgesdd Path 4t leaves
// rows m..n-1 of VT equal to the LQ-factorization orthogonal complement
// (dgelqf + dorglq). Replicate dlarfg/dgelq2/dorgl2 in double precision.
static void compute_basis_host(Basis* bs) {
  double L[11][20];
  for (int r = 0; r < 11; ++r)
    for (int c = 0; c < 20; ++c) L[r][c] = 0.0;
  for (int k = 1; k < NCELL; ++k) {
    double xk = (double)k / (double)NCELL;
    L[k - 1][2 * (k - 1)] = xk;
    L[k - 1][2 * (k - 1) + 1] = 1.0;
    L[k - 1][2 * k] = -xk;
    L[k - 1][2 * k + 1] = -1.0;
  }
  L[NCELL - 1][1] = 1.0;
  L[NCELL][2 * (NCELL - 1)] = 1.0;
  L[NCELL][2 * (NCELL - 1) + 1] = 1.0;

  double v[11][20];
  double tau[11];
  for (int i = 0; i < 11; ++i) {
    double alpha = L[i][i];
    double xn2 = 0.0;
    for (int l = i + 1; l < 20; ++l) xn2 += L[i][l] * L[i][l];
    double xnorm = sqrt(xn2);
    for (int l = 0; l < 20; ++l) v[i][l] = 0.0;
    v[i][i] = 1.0;
    if (xnorm == 0.0) {
      tau[i] = 0.0;
    } else {
      double beta = sqrt(alpha * alpha + xn2);
      if (alpha >= 0.0) beta = -beta;        // dlarfg: beta = -sign(alpha)*norm
      tau[i] = (beta - alpha) / beta;
      double sc = 1.0 / (alpha - beta);
      for (int l = i + 1; l < 20; ++l) v[i][l] = L[i][l] * sc;
      L[i][i] = beta;
      for (int j = i + 1; j < 11; ++j) {
        double w = 0.0;
        for (int l = i; l < 20; ++l) w += L[j][l] * v[i][l];
        w *= tau[i];
        for (int l = i; l < 20; ++l) L[j][l] -= w * v[i][l];
      }
    }
  }
  for (int j = 11; j < 20; ++j) {
    double q[20];
    for (int l = 0; l < 20; ++l) q[l] = 0.0;
    q[j] = 1.0;
    for (int i = 10; i >= 0; --i) {
      double w = 0.0;
      for (int l = i; l < 20; ++l) w += v[i][l] * q[l];
      w *= tau[i];
      for (int l = i; l < 20; ++l) q[l] -= w * v[i][l];
    }
    for (int l = 0; l < 20; ++l) bs->Bt[j - 11][l] = (float)q[l];
  }
}

// Fold W3B[r][l] = sum_t w3[r*9+t]*Bt[t][l] (10x20) and b3B[l] = sum_t b3[t]*Bt[t][l]
// per MLP into ws: [m1: 200 W + 20 b][m2: 200 W + 20 b] floats.
__global__ void fold_kernel(const float* __restrict__ w3_1, const float* __restrict__ b3_1,
                            const float* __restrict__ w3_2, const float* __restrict__ b3_2,
                            float* __restrict__ ws, Basis bb) {
  for (int f = threadIdx.x; f < 440; f += THREADS) {
    int m = f / 220;
    int j = f % 220;
    const float* w3 = (m == 0) ? w3_1 : w3_2;
    const float* b3 = (m == 0) ? b3_1 : b3_2;
    float val = 0.0f;
    if (j < 200) {
      int r = j / 20, l = j % 20;
      for (int t = 0; t < DDIM; ++t) val += w3[r * DDIM + t] * bb.Bt[t][l];
    } else {
      int l = j - 200;
      for (int t = 0; t < DDIM; ++t) val += b3[t] * bb.Bt[t][l];
    }
    ws[f] = val;
  }
}

// MLP (1->10->10->10) then A = h2 @ W3B + b3B written to this thread's LDS column.
__device__ __forceinline__ void mlp_A(float xin,
    const float* __restrict__ w0, const float* __restrict__ b0,
    const float* __restrict__ w1, const float* __restrict__ b1,
    const float* __restrict__ w2, const float* __restrict__ b2,
    const float* __restrict__ wbf,     // 220 floats: 100 f32x2 W3B pairs + 10 f32x2 b3B pairs
    f32x2* abcol) {
  const f32x2* w0p = (const f32x2*)w0;
  const f32x2* b0p = (const f32x2*)b0;
  const f32x2* w1p = (const f32x2*)w1;
  const f32x2* b1p = (const f32x2*)b1;
  const f32x2* w2p = (const f32x2*)w2;
  const f32x2* b2p = (const f32x2*)b2;
  const f32x2* WB  = (const f32x2*)wbf;

  f32x2 h0[5], h1[5], h2[5];
  f32x2 xx = {xin, xin};
#pragma unroll
  for (int p = 0; p < 5; ++p) h0[p] = fma2(xx, w0p[p], b0p[p]);

#pragma unroll
  for (int p = 0; p < 5; ++p) h1[p] = b1p[p];
#pragma unroll
  for (int r = 0; r < 10; ++r) {
    float h = h0[r >> 1][r & 1];
    f32x2 hh = {h, h};
#pragma unroll
    for (int p = 0; p < 5; ++p) h1[p] = fma2(hh, w1p[r * 5 + p], h1[p]);
  }
  f32x2 zero = {0.0f, 0.0f};
#pragma unroll
  for (int p = 0; p < 5; ++p) h1[p] = max2(h1[p], zero);

#pragma unroll
  for (int p = 0; p < 5; ++p) h2[p] = b2p[p];
#pragma unroll
  for (int r = 0; r < 10; ++r) {
    float h = h1[r >> 1][r & 1];
    f32x2 hh = {h, h};
#pragma unroll
    for (int p = 0; p < 5; ++p) h2[p] = fma2(hh, w2p[r * 5 + p], h2[p]);
  }
#pragma unroll
  for (int p = 0; p < 5; ++p) h2[p] = max2(h2[p], zero);

  f32x2 acc[NCELL];
#pragma unroll
  for (int l = 0; l < NCELL; ++l) acc[l] = WB[100 + l];   // b3B pairs
#pragma unroll
  for (int r = 0; r < 10; ++r) {
    float h = h2[r >> 1][r & 1];
    f32x2 hh = {h, h};
#pragma unroll
    for (int l = 0; l < NCELL; ++l) acc[l] = fma2(hh, WB[r * 10 + l], acc[l]);
  }
#pragma unroll
  for (int l = 0; l < NCELL; ++l) abcol[l * THREADS] = acc[l];
}

__device__ __forceinline__ void flow_dev(float x0, const f32x2* abcol,
                                         float& zo, float& ldo) {
  float phi = x0;
  float t = 1.0f;
  float ld = 0.0f;
  int c = (int)(x0 * 10.0f);
  c = c < 0 ? 0 : (c > 9 ? 9 : c);
  for (int it = 0; it < NCELL; ++it) {
    f32x2 ab = abcol[c * THREADS];
    float a = ab[0], b = ab[1];
    float v = fmaf(a, phi, b);
    bool lin = fabsf(a) < 1e-10f;
    float sa = lin ? 1.0f : a;
    float rsa = __builtin_amdgcn_rcpf(sa);       // v_rcp_f32
    float xc = ((v >= 0.0f) ? (float)(c + 1) : (float)c) * 0.1f;
    float bsa = b * rsa;
    float den = phi + bsa;
    den = (fabsf(den) < 1e-30f) ? 1e-30f : den;
    float ratio = (xc + bsa) * __builtin_amdgcn_rcpf(den);
    float t_exp = __logf(fmaxf(ratio, 1e-30f)) * rsa;   // v_log_f32
    float sb = (fabsf(b) < 1e-30f) ? 1.0f : b;
    float thit = lin ? ((xc - phi) * __builtin_amdgcn_rcpf(sb)) : t_exp;
    thit = (fabsf(v) < 1e-14f) ? __builtin_inff() : thit;
    bool cross = thit < t;
    float dt = cross ? thit : t;
    float E = __expf(a * dt);                    // v_exp_f32
    float phi_lin = fmaf(b, dt, phi);
    float phi_exp = fmaf(phi + bsa, E, -bsa);
    float phi_new = lin ? phi_lin : phi_exp;
    phi_new = cross ? xc : phi_new;
    bool active = t > 0.0f;
    phi = active ? phi_new : phi;
    ld += active ? a * dt : 0.0f;
    t = active ? (t - dt) : t;
    int cstep = (v >= 0.0f) ? 1 : -1;
    int cn = c + cstep;
    cn = cn < 0 ? 0 : (cn > 9 ? 9 : cn);
    c = (active && cross) ? cn : c;
    // wave-uniform early exit: inactive lanes never change state.
    if (__all(t <= 0.0f)) break;
  }
  zo = phi;
  ldo = ld;
}

__global__ __launch_bounds__(THREADS, 4) void cpab2d_kernel(
    const float* __restrict__ x,
    const float* __restrict__ m1w0, const float* __restrict__ m1b0,
    const float* __restrict__ m1w1, const float* __restrict__ m1b1,
    const float* __restrict__ m1w2, const float* __restrict__ m1b2,
    const float* __restrict__ m2w0, const float* __restrict__ m2b0,
    const float* __restrict__ m2w1, const float* __restrict__ m2b1,
    const float* __restrict__ m2w2, const float* __restrict__ m2b2,
    const float* __restrict__ wsf,
    float* __restrict__ out, int n) {
  __shared__ f32x2 AB[NCELL][THREADS];   // [cell][tid] -> conflict-free dyn read
  int i = blockIdx.x * THREADS + threadIdx.x;
  if (i >= n) return;

  float2 xi = reinterpret_cast<const float2*>(x)[i];
  // xs = x[:, [1,0]]: x1 = x[:,1], x2 = x[:,0]; both clipped first
  float x2v = fminf(fmaxf(xi.x, 1e-7f), 1.0f - 1e-7f);
  float x1v = fminf(fmaxf(xi.y, 1e-7f), 1.0f - 1e-7f);

  f32x2* abcol = &AB[0][threadIdx.x];

  // theta2 = mlp(x1, m2); z2,g2 = flow(x2, theta2)
  mlp_A(x1v, m2w0, m2b0, m2w1, m2b1, m2w2, m2b2, wsf + 220, abcol);
  float z2, ld2;
  flow_dev(x2v, abcol, z2, ld2);

  // theta1 = mlp(z2, m1); z1,g1 = flow(x1, theta1)
  mlp_A(z2, m1w0, m1b0, m1w1, m1b1, m1w2, m1b2, wsf, abcol);
  float z1, ld1;
  flow_dev(x1v, abcol, z1, ld1);

  // z = [z2, z1]; log_dz_dx = [ld2, ld1]
  reinterpret_cast<float2*>(out)[i] = make_float2(z2, z1);
  reinterpret_cast<float2*>(out + 2 * (size_t)n)[i] = make_float2(ld2, ld1);
}

extern "C" void kernel_launch(void* const* d_in, const int* in_sizes, int n_in,
                              void* d_out, int out_size, void* d_ws, size_t ws_size,
                              hipStream_t stream) {
  const float* x    = (const float*)d_in[0];
  const float* m1w0 = (const float*)d_in[1];
  const float* m1b0 = (const float*)d_in[2];
  const float* m1w1 = (const float*)d_in[3];
  const float* m1b1 = (const float*)d_in[4];
  const float* m1w2 = (const float*)d_in[5];
  const float* m1b2 = (const float*)d_in[6];
  const float* m1w3 = (const float*)d_in[7];
  const float* m1b3 = (const float*)d_in[8];
  const float* m2w0 = (const float*)d_in[9];
  const float* m2b0 = (const float*)d_in[10];
  const float* m2w1 = (const float*)d_in[11];
  const float* m2b1 = (const float*)d_in[12];
  const float* m2w2 = (const float*)d_in[13];
  const float* m2b2 = (const float*)d_in[14];
  const float* m2w3 = (const float*)d_in[15];
  const float* m2b3 = (const float*)d_in[16];
  float* out = (float*)d_out;
  float* wsf = (float*)d_ws;
  int n = in_sizes[0] / 2;

  Basis bs;
  compute_basis_host(&bs);

  fold_kernel<<<1, THREADS, 0, stream>>>(m1w3, m1b3, m2w3, m2b3, wsf, bs);

  dim3 grid((n + THREADS - 1) / THREADS), block(THREADS);
  cpab2d_kernel<<<grid, block, 0, stream>>>(
      x, m1w0, m1b0, m1w1, m1b1, m1w2, m1b2,
      m2w0, m2b0, m2w1, m2b1, m2w2, m2b2,
      wsf, out, n);
}